// Round 3
// baseline (295.018 us; speedup 1.0000x reference)
//
#include <hip/hip_runtime.h>

// Recall over [B=32, F=512, T=2048]:
//   p_adj[b,f,t] = predicted[b, f==0?1:f, t==0?1:t]
//   out = sum(p_adj * (gt!=0)) / count(gt!=0), or 0 if count==0.
//
// R3: force memory-level parallelism. R2's compiler collapsed the 16-load
// prefetch pack to fit 40 VGPRs, leaving ~2 loads in flight (latency-bound,
// 2.3 TB/s effective). Here: interleaved p/g load pack, sched_barrier(0) to
// pin all 16 loads before any consumption, launch_bounds(256,1) so the
// allocator keeps the pack live in registers.

constexpr int B_ = 32;
constexpr int F_ = 512;
constexpr int T_ = 2048;
constexpr long long NTOT = (long long)B_ * F_ * T_;   // 2^25
constexpr int NQ      = (int)(NTOT >> 2);             // 8,388,608 quads
constexpr int BLK     = 256;
constexpr int NBLK    = 4096;
constexpr int PER_THR = 8;                            // NQ / (BLK*NBLK)
static_assert((long long)BLK * NBLK * PER_THR == NQ, "exact cover");

constexpr int EDGE_ITEMS = B_ * T_ + B_ * F_;         // 81,920
constexpr int EDGE_BLKS  = EDGE_ITEMS / BLK;          // 320

__device__ __forceinline__ void sched_fence() {
#if __has_builtin(__builtin_amdgcn_sched_barrier)
    __builtin_amdgcn_sched_barrier(0);
#else
    asm volatile("" ::: "memory");
#endif
}

// ---------------- block reduction helper ----------------
__device__ __forceinline__ void block_reduce(float& s, int& c) {
    #pragma unroll
    for (int off = 32; off > 0; off >>= 1) {
        s += __shfl_down(s, off, 64);
        c += __shfl_down(c, off, 64);
    }
    __shared__ float ss[4];
    __shared__ int   sc[4];
    int lane = threadIdx.x & 63, wave = threadIdx.x >> 6;
    if (lane == 0) { ss[wave] = s; sc[wave] = c; }
    __syncthreads();
    if (threadIdx.x == 0) {
        s = ss[0] + ss[1] + ss[2] + ss[3];
        c = sc[0] + sc[1] + sc[2] + sc[3];
    }
}

// ---------------- main branchless masked sum ----------------
__global__ __launch_bounds__(256, 1) void recall_main(
    const float4* __restrict__ p4,
    const int4* __restrict__ g4,
    float* __restrict__ bsum,
    unsigned int* __restrict__ bcnt)
{
    const unsigned tid    = blockIdx.x * BLK + threadIdx.x;
    const unsigned STRIDE = (unsigned)BLK * NBLK;      // 1,048,576 quads

    float4 p[PER_THR];
    int4   g[PER_THR];

    // Issue all 16 loads, interleaved p/g so consumption in k-order gives
    // incremental vmcnt waits. sched_barrier keeps them ahead of the math.
    #pragma unroll
    for (int k = 0; k < PER_THR; ++k) {
        size_t q = (size_t)tid + (size_t)k * STRIDE;
        p[k] = p4[q];
        g[k] = g4[q];
    }
    sched_fence();

    float lsum = 0.f;
    int   lcnt = 0;
    #pragma unroll
    for (int k = 0; k < PER_THR; ++k) {
        lcnt += (g[k].x != 0) + (g[k].y != 0) + (g[k].z != 0) + (g[k].w != 0);
        lsum += (g[k].x ? p[k].x : 0.f);
        lsum += (g[k].y ? p[k].y : 0.f);
        lsum += (g[k].z ? p[k].z : 0.f);
        lsum += (g[k].w ? p[k].w : 0.f);
    }

    block_reduce(lsum, lcnt);
    if (threadIdx.x == 0) {
        bsum[blockIdx.x] = lsum;
        bcnt[blockIdx.x] = (unsigned int)lcnt;
    }
}

// ---------------- edge-remap correction ----------------
// Items [0, B*T):          f==0 row  (all t; remap f->1, t->max(t,1))
// Items [B*T, B*T + B*F):  t==0 col, f>=1 only (remap t->1); f==0 cell
// is covered by the first range.
__global__ __launch_bounds__(256) void recall_edge(
    const float* __restrict__ pred,
    const int* __restrict__ gt,
    float* __restrict__ csum)
{
    unsigned idx = blockIdx.x * BLK + threadIdx.x;
    float corr = 0.f;
    if (idx < (unsigned)(B_ * T_)) {
        unsigned b = idx >> 11, t = idx & (T_ - 1);
        unsigned raw = (b << 20) | t;
        unsigned tp  = (t == 0u) ? 1u : t;
        unsigned adj = (b << 20) | (1u << 11) | tp;
        if (gt[raw]) corr = pred[adj] - pred[raw];
    } else {
        unsigned i2 = idx - (unsigned)(B_ * T_);
        unsigned b = i2 >> 9, f = i2 & (F_ - 1);
        if (f != 0u) {
            unsigned raw = (b << 20) | (f << 11);
            if (gt[raw]) corr = pred[raw + 1] - pred[raw];
        }
    }
    int dummy = 0;
    block_reduce(corr, dummy);
    if (threadIdx.x == 0) csum[blockIdx.x] = corr;
}

// ---------------- finalize ----------------
__global__ __launch_bounds__(256) void recall_fin(
    const float* __restrict__ bsum,
    const unsigned int* __restrict__ bcnt,
    const float* __restrict__ csum,
    float* __restrict__ out)
{
    float s = 0.f;
    int   c = 0;
    for (int j = threadIdx.x; j < NBLK; j += BLK) {
        s += bsum[j];
        c += (int)bcnt[j];
    }
    for (int j = threadIdx.x; j < EDGE_BLKS; j += BLK) s += csum[j];

    block_reduce(s, c);
    if (threadIdx.x == 0)
        out[0] = (c > 0) ? (s / (float)c) : 0.0f;
}

extern "C" void kernel_launch(void* const* d_in, const int* in_sizes, int n_in,
                              void* d_out, int out_size, void* d_ws, size_t ws_size,
                              hipStream_t stream)
{
    const float* pred = (const float*)d_in[0];
    const int*   gt   = (const int*)d_in[1];
    float*       out  = (float*)d_out;

    float*        bsum = (float*)d_ws;
    unsigned int* bcnt = (unsigned int*)((char*)d_ws + NBLK * sizeof(float));
    float*        csum = (float*)((char*)d_ws + 2 * NBLK * sizeof(float));

    recall_main<<<NBLK, BLK, 0, stream>>>((const float4*)pred, (const int4*)gt,
                                          bsum, bcnt);
    recall_edge<<<EDGE_BLKS, BLK, 0, stream>>>(pred, gt, csum);
    recall_fin<<<1, BLK, 0, stream>>>(bsum, bcnt, csum, out);
}